// Round 4
// baseline (130.543 us; speedup 1.0000x reference)
//
#include <hip/hip_runtime.h>

// x [8,128,96,96] fp32, W [384,128] fp32, out [8,128,96,96] fp32.
#define NB    8
#define CIN   128
#define HDIM  96
#define WDIM  96
#define HW    9216
#define TW    16     // interior tile width
#define TH    4      // interior tile height
#define HXW   18     // halo width
#define NHX   108    // halo pixels (18*6)
#define NHXP  112    // padded to 7 M-tiles of 16
#define NMT   7
#define KV_REC 272   // 256 B (k:2 heads x 32d + v: same, bf16) + 16 pad
#define Q_REC  144   // 128 B (2 heads x 32 d bf16) + 16 pad

typedef __bf16 bf16x8 __attribute__((ext_vector_type(8)));
typedef float  f32x4  __attribute__((ext_vector_type(4)));

__device__ __forceinline__ unsigned f2bf(float f) {
  unsigned u = __float_as_uint(f);
  return (u + 0x7fffu + ((u >> 16) & 1u)) >> 16;   // RNE
}
__device__ __forceinline__ unsigned pack2(float a, float b) {
  return f2bf(a) | (f2bf(b) << 16);
}
__device__ __forceinline__ float bflo(unsigned u) { return __uint_as_float(u << 16); }
__device__ __forceinline__ float bfhi(unsigned u) { return __uint_as_float(u & 0xffff0000u); }

// ---------------------------------------------------------------------------
// Prep: pack W [384][128] fp32 -> A-fragment-ordered bf16 (16x16x32 MFMA).
// Frag (ot,kb): lane l holds A[o=ot*16+(l&15)][c=kb*32+(l>>4)*8+j], j=0..7.
// ot 0..7 = q channels 0..127, 8..15 = k, 16..23 = v.  (verified r2/r3)
// ---------------------------------------------------------------------------
__global__ __launch_bounds__(256) void wpack_kernel(const float* __restrict__ W,
                                                    uint4* __restrict__ Wf) {
  const int u = blockIdx.x * 256 + threadIdx.x;   // 24 ot * 4 kb * 64 lanes
  const int lane = u & 63, kb = (u >> 6) & 3, ot = u >> 8;
  const int o = ot * 16 + (lane & 15);
  const int c0 = kb * 32 + (lane >> 4) * 8;
  const float4* w = (const float4*)(W + (size_t)o * CIN + c0);
  float4 w0 = w[0], w1 = w[1];
  uint4 r;
  r.x = pack2(w0.x, w0.y); r.y = pack2(w0.z, w0.w);
  r.z = pack2(w1.x, w1.y); r.w = pack2(w1.z, w1.w);
  Wf[u] = r;
}

// ---------------------------------------------------------------------------
// Fused: stage x halo -> MFMA qkv into LDS -> neighborhood attention -> out.
// Block = 16x4 interior tile, one head-pair (hp). Zero-filled x halo makes
// OOB k=v=0 exactly => no boundary predication anywhere in attention.
// ---------------------------------------------------------------------------
__global__ __launch_bounds__(256, 2) void fused_kernel(
    const float* __restrict__ x, const uint4* __restrict__ Wf,
    float* __restrict__ out) {
  __shared__ uint4 xs4[NMT * 4 * 64];            // 28672 B: x B-frags
  __shared__ uint4 kv4[NHXP * KV_REC / 16];      // 30464 B: k|v per halo px
  __shared__ uint4 q4[NHXP * Q_REC / 16];        // 16128 B: q per halo px

  const int t  = threadIdx.x;
  const int w0 = blockIdx.x * TW, h0 = blockIdx.y * TH;
  const int b  = blockIdx.z >> 1, hp = blockIdx.z & 1;

  // ---- Phase A: stage x halo tile as bf16 B-frags (zero-filled OOB) ----
#pragma unroll
  for (int i = 0; i < 7; ++i) {
    const int id  = i * 256 + t;          // 0..1791 = 16 c-octets * 112 hx
    const int oct = id / NHXP;
    const int hx  = id - oct * NHXP;
    const int r   = hx / HXW;
    const int ww  = hx - r * HXW;
    const int h = h0 - 1 + r, w = w0 - 1 + ww;
    const bool valid = (hx < NHX) && ((unsigned)h < HDIM) && ((unsigned)w < WDIM);
    float f[8];
    if (valid) {
      const float* xb = x + ((size_t)(b * CIN + oct * 8)) * HW + h * WDIM + w;
#pragma unroll
      for (int jv = 0; jv < 8; ++jv) f[jv] = xb[(size_t)jv * HW];
    } else {
#pragma unroll
      for (int jv = 0; jv < 8; ++jv) f[jv] = 0.f;
    }
    uint4 rv;
    rv.x = pack2(f[0], f[1]); rv.y = pack2(f[2], f[3]);
    rv.z = pack2(f[4], f[5]); rv.w = pack2(f[6], f[7]);
    xs4[((hx >> 4) * 4 + (oct >> 2)) * 64 + (oct & 3) * 16 + (hx & 15)] = rv;
  }
  __syncthreads();

  // ---- Phase B: GEMM q/k/v = W*x for all halo px, results -> LDS bf16 ----
  {
    const int lane = t & 63, wv = t >> 6;
    const int colp = lane & 15, quad = lane >> 4;
    uint4 bfr[NMT][4];                     // 112 VGPRs: whole x tile
#pragma unroll
    for (int mt = 0; mt < NMT; ++mt)
#pragma unroll
      for (int kb = 0; kb < 4; ++kb)
        bfr[mt][kb] = xs4[(mt * 4 + kb) * 64 + lane];

#pragma unroll
    for (int jj = 0; jj < 3; ++jj) {       // wave wv owns j = wv*3..wv*3+2 of 12
      const int j = wv * 3 + jj;
      const int which = j >> 2, jo = j & 3;     // which: 0=q,1=k,2=v
      const int ot = which * 8 + hp * 4 + jo;   // original Wf ot index
      uint4 af[4];
#pragma unroll
      for (int kb = 0; kb < 4; ++kb) af[kb] = Wf[(ot * 4 + kb) * 64 + lane];
      const int lc = jo * 16 + quad * 4;        // local channel 0..60 (g2*32+d)
      char* base; int rec;
      if (which == 0) { base = (char*)q4 + lc * 2; rec = Q_REC; }
      else { base = (char*)kv4 + (which - 1) * 128 + lc * 2; rec = KV_REC; }
#pragma unroll
      for (int mt = 0; mt < NMT; ++mt) {
        f32x4 acc = {0.f, 0.f, 0.f, 0.f};
#pragma unroll
        for (int kb = 0; kb < 4; ++kb)
          acc = __builtin_amdgcn_mfma_f32_16x16x32_bf16(
              *(bf16x8*)&af[kb], *(bf16x8*)&bfr[mt][kb], acc, 0, 0, 0);
        uint2 st;                                // 4 bf16: lc..lc+3
        st.x = pack2(acc[0], acc[1]);
        st.y = pack2(acc[2], acc[3]);
        *(uint2*)(base + (mt * 16 + colp) * rec) = st;   // col = halo px
      }
    }
  }
  __syncthreads();

  // ---- Phase C: attention. thread = (px 0..63, g2 0..1, dh 0..1) ----
  {
    const int px = t >> 2, g2 = (t >> 1) & 1, dh = t & 1;
    const int pr = px >> 4, pw = px & 15;
    const int hx0 = (pr + 1) * HXW + pw + 1;
    const int hoff = g2 * 64 + dh * 32;

    float q[16];
    {
      const uint4* qp = (const uint4*)((const char*)q4 + hx0 * Q_REC + hoff);
      uint4 u0 = qp[0], u1 = qp[1];
      q[0]=bflo(u0.x);  q[1]=bfhi(u0.x);  q[2]=bflo(u0.y);  q[3]=bfhi(u0.y);
      q[4]=bflo(u0.z);  q[5]=bfhi(u0.z);  q[6]=bflo(u0.w);  q[7]=bfhi(u0.w);
      q[8]=bflo(u1.x);  q[9]=bfhi(u1.x);  q[10]=bflo(u1.y); q[11]=bfhi(u1.y);
      q[12]=bflo(u1.z); q[13]=bfhi(u1.z); q[14]=bflo(u1.w); q[15]=bfhi(u1.w);
    }

    float att[9];
#pragma unroll
    for (int nn = 0; nn < 9; ++nn) {
      const int hxn = hx0 + (nn / 3 - 1) * HXW + (nn % 3 - 1);
      const uint4* kp = (const uint4*)((const char*)kv4 + hxn * KV_REC + hoff);
      uint4 k0 = kp[0], k1 = kp[1];
      float dot = 0.f;
      dot = fmaf(q[0],  bflo(k0.x), dot); dot = fmaf(q[1],  bfhi(k0.x), dot);
      dot = fmaf(q[2],  bflo(k0.y), dot); dot = fmaf(q[3],  bfhi(k0.y), dot);
      dot = fmaf(q[4],  bflo(k0.z), dot); dot = fmaf(q[5],  bfhi(k0.z), dot);
      dot = fmaf(q[6],  bflo(k0.w), dot); dot = fmaf(q[7],  bfhi(k0.w), dot);
      dot = fmaf(q[8],  bflo(k1.x), dot); dot = fmaf(q[9],  bfhi(k1.x), dot);
      dot = fmaf(q[10], bflo(k1.y), dot); dot = fmaf(q[11], bfhi(k1.y), dot);
      dot = fmaf(q[12], bflo(k1.z), dot); dot = fmaf(q[13], bfhi(k1.z), dot);
      dot = fmaf(q[14], bflo(k1.w), dot); dot = fmaf(q[15], bfhi(k1.w), dot);
      dot += __shfl_xor(dot, 1);                 // combine d-halves (dh pair)
      att[nn] = dot * 0.17677669529663687f;      // 1/sqrt(32); OOB => exact 0
    }

    float m = att[0];
#pragma unroll
    for (int nn = 1; nn < 9; ++nn) m = fmaxf(m, att[nn]);
    float s = 0.f;
#pragma unroll
    for (int nn = 0; nn < 9; ++nn) { att[nn] = __expf(att[nn] - m); s += att[nn]; }
    const float inv = 1.0f / s;

    float acc[16];
#pragma unroll
    for (int i = 0; i < 16; ++i) acc[i] = 0.f;
#pragma unroll
    for (int nn = 0; nn < 9; ++nn) {
      const int hxn = hx0 + (nn / 3 - 1) * HXW + (nn % 3 - 1);
      const uint4* vp = (const uint4*)((const char*)kv4 + hxn * KV_REC + 128 + hoff);
      uint4 v0 = vp[0], v1 = vp[1];
      const float wn = att[nn] * inv;            // OOB v == 0 => contributes 0
      acc[0]  = fmaf(wn, bflo(v0.x), acc[0]);  acc[1]  = fmaf(wn, bfhi(v0.x), acc[1]);
      acc[2]  = fmaf(wn, bflo(v0.y), acc[2]);  acc[3]  = fmaf(wn, bfhi(v0.y), acc[3]);
      acc[4]  = fmaf(wn, bflo(v0.z), acc[4]);  acc[5]  = fmaf(wn, bfhi(v0.z), acc[5]);
      acc[6]  = fmaf(wn, bflo(v0.w), acc[6]);  acc[7]  = fmaf(wn, bfhi(v0.w), acc[7]);
      acc[8]  = fmaf(wn, bflo(v1.x), acc[8]);  acc[9]  = fmaf(wn, bfhi(v1.x), acc[9]);
      acc[10] = fmaf(wn, bflo(v1.y), acc[10]); acc[11] = fmaf(wn, bfhi(v1.y), acc[11]);
      acc[12] = fmaf(wn, bflo(v1.z), acc[12]); acc[13] = fmaf(wn, bfhi(v1.z), acc[13]);
      acc[14] = fmaf(wn, bflo(v1.w), acc[14]); acc[15] = fmaf(wn, bfhi(v1.w), acc[15]);
    }

    // out [b][128][96][96]; ch = (hp*2+g2)*32 + dh*16 + i; lanes along w
    float* ob = out + ((size_t)(b * CIN + hp * 64 + g2 * 32 + dh * 16)) * HW
                + (h0 + pr) * WDIM + w0 + pw;
#pragma unroll
    for (int i = 0; i < 16; ++i) ob[(size_t)i * HW] = acc[i];
  }
}

extern "C" void kernel_launch(void* const* d_in, const int* in_sizes, int n_in,
                              void* d_out, int out_size, void* d_ws, size_t ws_size,
                              hipStream_t stream) {
  (void)in_sizes; (void)n_in; (void)out_size; (void)ws_size;
  const float* x = (const float*)d_in[0];   // [8,128,96,96]
  const float* W = (const float*)d_in[1];   // [384,128]
  float* out = (float*)d_out;
  uint4* Wf = (uint4*)d_ws;                 // 24*4*64*16 = 98304 B

  wpack_kernel<<<24, 256, 0, stream>>>(W, Wf);
  fused_kernel<<<dim3(WDIM / TW, HDIM / TH, NB * 2), 256, 0, stream>>>(x, Wf, out);
}